// Round 8
// baseline (1288.162 us; speedup 1.0000x reference)
//
#include <hip/hip_runtime.h>
#include <hip/hip_fp16.h>
#include <math.h>
#include <stdint.h>

#define B_   512
#define L_   128
#define K_   9
#define NE   50000
#define ZD   16
#define TE   32
#define XE   128
#define EP   8
#define H_   128
#define G4   512
#define OD   32
#define IN0  184
#define MKD  168

typedef uint32_t u32;
typedef _Float16 half2v __attribute__((ext_vector_type(2)));
typedef _Float16 half8  __attribute__((ext_vector_type(8)));
typedef float    f32x4  __attribute__((ext_vector_type(4)));

__device__ __forceinline__ float sigm(float x) {
    x = fminf(fmaxf(x, -30.f), 30.f);
    return 1.f / (1.f + expf(-x));
}
__device__ __forceinline__ float tanh_f(float x) {
    x = fminf(fmaxf(x, -15.f), 15.f);
    float e = expf(2.f * x);
    return (e - 1.f) / (e + 1.f);
}
__device__ __forceinline__ float dot2f(u32 w, u32 h, float acc) {
#if __has_builtin(__builtin_amdgcn_fdot2)
    union { u32 u; half2v v; } a, b;
    a.u = w; b.u = h;
    return __builtin_amdgcn_fdot2(a.v, b.v, acc, false);
#else
    union { u32 u; __half2 h2; } a, b;
    a.u = w; b.u = h;
    float2 fa = __half22float2(a.h2), fb = __half22float2(b.h2);
    return fmaf(fa.x, fb.x, fmaf(fa.y, fb.y, acc));
#endif
}
__device__ __forceinline__ u32 packh(float lo, float hi) {
    union { __half2 h; u32 u; } p;
    p.h = __halves2half2(__float2half(lo), __float2half(hi));
    return p.u;
}
__device__ __forceinline__ f32x4 cvt4h(uint2 p) {
    union { u32 u; half2v v; } a, b;
    a.u = p.x; b.u = p.y;
    f32x4 r;
    r[0] = (float)a.v[0]; r[1] = (float)a.v[1];
    r[2] = (float)b.v[0]; r[3] = (float)b.v[1];
    return r;
}

// ---------------------------------------------------------------------------
// kW2: pack all weights (f16 pairs) + bias sums.  All big matrices row-major:
//   wih0p [512][96]  (K=192, cols 184..191 zero)   @ 0
//   whh0  [512][64]                                @ 49152
//   wih1p [512][64]                                @ 81920
//   whh1  [512][64]                                @ 114688
//   wih2p [512][64]                                @ 147456
//   whh2  [512][64]                                @ 180224
//   wap   [32][64]                                 @ 212992
//   wmxp  [32][68]                                 @ 215040
//   wmtp  [32][68]                                 @ 217216
//   watp0 [32][16]                                 @ 219392
//   bsum  [3][512] f32                             @ 219904
// ---------------------------------------------------------------------------
__global__ void __launch_bounds__(256)
kW2(const float* __restrict__ w_ih0, const float* __restrict__ w_hh0,
    const float* __restrict__ w_ih1, const float* __restrict__ w_hh1,
    const float* __restrict__ w_ih2, const float* __restrict__ w_hh2,
    const float* __restrict__ wax, const float* __restrict__ wmx,
    const float* __restrict__ wmt, const float* __restrict__ wat,
    const float* __restrict__ b_ih0, const float* __restrict__ b_hh0,
    const float* __restrict__ b_ih1, const float* __restrict__ b_hh1,
    const float* __restrict__ b_ih2, const float* __restrict__ b_hh2,
    u32* __restrict__ wsu)
{
    int gid = blockIdx.x * 256 + threadIdx.x;
    if (gid < 49152) {
        int g = gid / 96, c = gid % 96;
        wsu[gid] = (c < 92) ? packh(w_ih0[g * IN0 + 2 * c], w_ih0[g * IN0 + 2 * c + 1]) : 0u;
    } else if (gid < 81920) {
        int e = gid - 49152; int g = e >> 6, c = e & 63;
        wsu[gid] = packh(w_hh0[g * H_ + 2 * c], w_hh0[g * H_ + 2 * c + 1]);
    } else if (gid < 114688) {
        int e = gid - 81920; int g = e >> 6, c = e & 63;
        wsu[gid] = packh(w_ih1[g * H_ + 2 * c], w_ih1[g * H_ + 2 * c + 1]);
    } else if (gid < 147456) {
        int e = gid - 114688; int g = e >> 6, c = e & 63;
        wsu[gid] = packh(w_hh1[g * H_ + 2 * c], w_hh1[g * H_ + 2 * c + 1]);
    } else if (gid < 180224) {
        int e = gid - 147456; int g = e >> 6, c = e & 63;
        wsu[gid] = packh(w_ih2[g * H_ + 2 * c], w_ih2[g * H_ + 2 * c + 1]);
    } else if (gid < 212992) {
        int e = gid - 180224; int g = e >> 6, c = e & 63;
        wsu[gid] = packh(w_hh2[g * H_ + 2 * c], w_hh2[g * H_ + 2 * c + 1]);
    } else if (gid < 215040) {
        int e = gid - 212992; int o = e >> 6, c = e & 63;
        wsu[gid] = packh(wax[o * H_ + 2 * c], wax[o * H_ + 2 * c + 1]);
    } else if (gid < 217216) {
        int e = gid - 215040; int o = e / 68, c = e % 68;
        int col = c < 64 ? 2 * c : 160 + 2 * (c - 64);
        wsu[gid] = packh(wmx[o * MKD + col], wmx[o * MKD + col + 1]);
    } else if (gid < 219392) {
        int e = gid - 217216; int o = e / 68, c = e % 68;
        int col = c < 64 ? 2 * c : 160 + 2 * (c - 64);
        wsu[gid] = packh(wmt[o * MKD + col], wmt[o * MKD + col + 1]);
    } else if (gid < 219904) {
        int e = gid - 219392; int o = e >> 4, c = e & 15;
        wsu[gid] = packh(wat[o * 64 + 2 * c], wat[o * 64 + 2 * c + 1]);
    } else if (gid < 221440) {
        int e = gid - 219904; int layer = e >> 9, g = e & 511;
        float v;
        if (layer == 0)      v = b_ih0[g] + b_hh0[g];
        else if (layer == 1) v = b_ih1[g] + b_hh1[g];
        else                 v = b_ih2[g] + b_hh2[g];
        ((float*)wsu)[gid] = v;
    }
}

// ---------------------------------------------------------------------------
// kT: dt tables (48 x 96): [tmx(+bmx) | tmt(+bmt) | tat(+bat)]
// ---------------------------------------------------------------------------
__global__ void __launch_bounds__(256)
kT(const float* __restrict__ t_emb,
   const float* __restrict__ wmx, const float* __restrict__ wmt,
   const float* __restrict__ wat,
   const float* __restrict__ bmx, const float* __restrict__ bmt,
   const float* __restrict__ bat, float* __restrict__ ttab)
{
    int gid = blockIdx.x * 256 + threadIdx.x;
    if (gid >= 48 * 96) return;
    int dt = gid / 96, o96 = gid % 96;
    const float* te = t_emb + dt * TE;
    int o = o96 & 31;
    float acc;
    const float* w;
    if (o96 < 32)      { acc = bmx[o]; w = wmx + o * MKD + XE; }
    else if (o96 < 64) { acc = bmt[o]; w = wmt + o * MKD + XE; }
    else               { acc = bat[o]; w = wat + o * 64 + TE; }
    for (int d = 0; d < TE; ++d) acc = fmaf(te[d], w[d], acc);
    ttab[dt * 96 + o96] = acc;
}

// ---------------------------------------------------------------------------
// kE: per-edge tables (50000 x 96): [emx | emt | eat]  (no biases)
// ---------------------------------------------------------------------------
__global__ void __launch_bounds__(256)
kE(const float* __restrict__ x_emb, const float* __restrict__ eprop,
   const float* __restrict__ tcost,
   const u32* __restrict__ wmxp, const u32* __restrict__ wmtp,
   const u32* __restrict__ watp0, float* __restrict__ etab)
{
    __shared__ uint4 smx[544], smt[544], sat[128];
    int tid = threadIdx.x;
    for (int i = tid; i < 544; i += 256) {
        smx[i] = ((const uint4*)wmxp)[i];
        smt[i] = ((const uint4*)wmtp)[i];
    }
    if (tid < 128) sat[tid] = ((const uint4*)watp0)[tid];
    __syncthreads();
    int e = blockIdx.x * 256 + tid;
    if (e >= NE) return;

    u32 in[68], tin[16];
    const float* xr = x_emb + (size_t)e * XE;
#pragma unroll
    for (int c = 0; c < 64; ++c) in[c] = packh(xr[2 * c], xr[2 * c + 1]);
    const float* er = eprop + (size_t)e * EP;
#pragma unroll
    for (int c = 0; c < 4; ++c) in[64 + c] = packh(er[2 * c], er[2 * c + 1]);
    const float* tr = tcost + (size_t)e * TE;
#pragma unroll
    for (int c = 0; c < 16; ++c) tin[c] = packh(tr[2 * c], tr[2 * c + 1]);

    float* outp = etab + (size_t)e * 96;
    for (int o = 0; o < OD; ++o) {
        float ax = 0.f, am = 0.f, aa = 0.f;
#pragma unroll
        for (int c4 = 0; c4 < 17; ++c4) {
            uint4 wx = smx[o * 17 + c4], wt = smt[o * 17 + c4];
            ax = dot2f(wx.x, in[c4 * 4 + 0], ax);
            ax = dot2f(wx.y, in[c4 * 4 + 1], ax);
            ax = dot2f(wx.z, in[c4 * 4 + 2], ax);
            ax = dot2f(wx.w, in[c4 * 4 + 3], ax);
            am = dot2f(wt.x, in[c4 * 4 + 0], am);
            am = dot2f(wt.y, in[c4 * 4 + 1], am);
            am = dot2f(wt.z, in[c4 * 4 + 2], am);
            am = dot2f(wt.w, in[c4 * 4 + 3], am);
        }
#pragma unroll
        for (int c4 = 0; c4 < 4; ++c4) {
            uint4 wa = sat[o * 4 + c4];
            aa = dot2f(wa.x, tin[c4 * 4 + 0], aa);
            aa = dot2f(wa.y, tin[c4 * 4 + 1], aa);
            aa = dot2f(wa.z, tin[c4 * 4 + 2], aa);
            aa = dot2f(wa.w, tin[c4 * 4 + 3], aa);
        }
        outp[o] = ax; outp[32 + o] = am; outp[64 + o] = aa;
    }
}

// ---------------------------------------------------------------------------
// kAP: build layer-0 A panel [65536][96 u32] (K=192, pad 184..191 = 0)
// ---------------------------------------------------------------------------
__global__ void __launch_bounds__(512)
kAP(const int* __restrict__ x, const int* __restrict__ dpt,
    const float* __restrict__ z, const float* __restrict__ eprop,
    const float* __restrict__ x_emb, const float* __restrict__ t_emb,
    u32* __restrict__ A0)
{
    int tid = threadIdx.x;
    int i = tid >> 2, q = tid & 3;
    int bl = blockIdx.x * 128 + i;
    int xt = x[bl], dt = dpt[bl];
    int b = bl >> 7, l = bl & 127;
    const float* zr = z + ((size_t)l * B_ + b) * ZD;
    const float* xr = x_emb + (size_t)xt * XE;
    const float* tr = t_emb + (size_t)dt * TE;
    const float* er = eprop + (size_t)xt * EP;
    u32* outp = A0 + (size_t)bl * 96;
#pragma unroll
    for (int cc = 0; cc < 24; ++cc) {
        int c = q * 24 + cc;
        float lo, hi;
        if (c < 8)       { lo = zr[2 * c];          hi = zr[2 * c + 1]; }
        else if (c < 72) { lo = xr[2 * (c - 8)];    hi = xr[2 * (c - 8) + 1]; }
        else if (c < 88) { lo = tr[2 * (c - 72)];   hi = tr[2 * (c - 72) + 1]; }
        else if (c < 92) { lo = er[2 * (c - 88)];   hi = er[2 * (c - 88) + 1]; }
        else             { lo = 0.f;                hi = 0.f; }
        outp[c] = packh(lo, hi);
    }
}

// ---------------------------------------------------------------------------
// kGm<KC>: MFMA GEMM.  Out[M][512] (f16) = A[M][KC*32] @ W[512][KC*32]^T + bsum.
// (layer-0 input gates only)
// ---------------------------------------------------------------------------
template<int KC>
__global__ void __launch_bounds__(512, 2)
kGm(const _Float16* __restrict__ A, const u32* __restrict__ Wp,
    const float* __restrict__ bsum, _Float16* __restrict__ Out)
{
    const int K = KC * 32;
    int tid = threadIdx.x;
    int w = tid >> 6, l = tid & 63;
    int lr = l & 15, lq = l >> 4;
    int bl0 = blockIdx.x * 64;

    half8 a[4][KC];
#pragma unroll
    for (int t = 0; t < 4; ++t)
#pragma unroll
        for (int c = 0; c < KC; ++c)
            a[t][c] = *reinterpret_cast<const half8*>(
                A + (size_t)(bl0 + t * 16 + lr) * K + c * 32 + lq * 8);

#pragma unroll
    for (int pass = 0; pass < 4; ++pass) {
        int g = pass * 128 + w * 16 + lr;
        half8 bfr[KC];
#pragma unroll
        for (int c = 0; c < KC; ++c)
            bfr[c] = *reinterpret_cast<const half8*>(
                (const _Float16*)Wp + (size_t)g * K + c * 32 + lq * 8);
        float bias = bsum[g];
#pragma unroll
        for (int t = 0; t < 4; ++t) {
            f32x4 acc = {0.f, 0.f, 0.f, 0.f};
#pragma unroll
            for (int c = 0; c < KC; ++c)
                acc = __builtin_amdgcn_mfma_f32_16x16x32_f16(a[t][c], bfr[c], acc, 0, 0, 0);
#pragma unroll
            for (int j = 0; j < 4; ++j) {
                int item = bl0 + t * 16 + lq * 4 + j;
                Out[(size_t)item * G4 + g] = (_Float16)(acc[j] + bias);
            }
        }
    }
}

// ---------------------------------------------------------------------------
// kRecM<MODE>: MFMA LSTM recurrence.  32 blocks x 512 threads (8 waves);
// block owns 16 batch rows.  gates[512x16] = W @ [x;h] per step.
// Wave w gate-tiles: {16w, 128+16w, 256+16w, 384+16w} -> lane's 4 acc regs at
// index j are (i,f,g,o) of h-dim hd=16w+lq*4+j, row=lr -> update is per-lane.
// W fragments resident in VGPRs (64/lane per matrix).  h double-buffered in
// LDS [16][136] f16 (272B stride: 16B-aligned, <=2-way banks = free).
// MODE 0: acc init from gin (precomputed input gates, layer 0).
// MODE 1: acc init from bias; input-GEMM fused via resident W_ih fragments,
//         x = prev-layer h-seq streamed from global.
// ---------------------------------------------------------------------------
template<int MODE>
__global__ void __launch_bounds__(512, 2)
kRecM(const _Float16* __restrict__ gin, const _Float16* __restrict__ xseq,
      const u32* __restrict__ whh, const u32* __restrict__ wih,
      const float* __restrict__ bias, _Float16* __restrict__ hout)
{
    constexpr int RS = 136;                 // LDS row stride (f16)
    __shared__ _Float16 hl[2][16][RS];
    const int tid = threadIdx.x;
    const int w   = tid >> 6;
    const int l   = tid & 63;
    const int lr  = l & 15;
    const int lq  = l >> 4;
    const int r0  = blockIdx.x * 16;

    const int tb0 = 16 * w, tb1 = 128 + 16 * w, tb2 = 256 + 16 * w, tb3 = 384 + 16 * w;

    // resident W_hh fragments: A row = lane&15 (gate), k = kc*32 + lq*8 + e
    half8 ahh[4][4];
    const _Float16* whhp = (const _Float16*)whh;
#pragma unroll
    for (int kc = 0; kc < 4; ++kc) {
        ahh[0][kc] = *(const half8*)(whhp + (size_t)(tb0 + lr) * H_ + kc * 32 + lq * 8);
        ahh[1][kc] = *(const half8*)(whhp + (size_t)(tb1 + lr) * H_ + kc * 32 + lq * 8);
        ahh[2][kc] = *(const half8*)(whhp + (size_t)(tb2 + lr) * H_ + kc * 32 + lq * 8);
        ahh[3][kc] = *(const half8*)(whhp + (size_t)(tb3 + lr) * H_ + kc * 32 + lq * 8);
    }
    half8 aih[4][4];
    if (MODE == 1) {
        const _Float16* wihp = (const _Float16*)wih;
#pragma unroll
        for (int kc = 0; kc < 4; ++kc) {
            aih[0][kc] = *(const half8*)(wihp + (size_t)(tb0 + lr) * H_ + kc * 32 + lq * 8);
            aih[1][kc] = *(const half8*)(wihp + (size_t)(tb1 + lr) * H_ + kc * 32 + lq * 8);
            aih[2][kc] = *(const half8*)(wihp + (size_t)(tb2 + lr) * H_ + kc * 32 + lq * 8);
            aih[3][kc] = *(const half8*)(wihp + (size_t)(tb3 + lr) * H_ + kc * 32 + lq * 8);
        }
    }

    // bias init (MODE 1): f32x4 per tile, gates tb + lq*4 + j
    f32x4 binit[4];
    if (MODE == 1) {
#pragma unroll
        for (int j = 0; j < 4; ++j) {
            binit[0][j] = bias[tb0 + lq * 4 + j];
            binit[1][j] = bias[tb1 + lq * 4 + j];
            binit[2][j] = bias[tb2 + lq * 4 + j];
            binit[3][j] = bias[tb3 + lq * 4 + j];
        }
    }

    // zero LDS buffer 0 (h at t=0 is zero)
    {
        _Float16* hp = &hl[0][0][0];
        for (int i = tid; i < 16 * RS; i += 512) hp[i] = (_Float16)0.f;
    }

    // prefetch state
    const _Float16* gb = (MODE == 0) ? gin + (size_t)(r0 + lr) * L_ * G4 : nullptr;
    const _Float16* xb = (MODE == 1) ? xseq + (size_t)(r0 + lr) * L_ * H_ : nullptr;
    uint2 gpre[4];
    half8 bx[4];
    if (MODE == 0) {
        gpre[0] = *(const uint2*)(gb + tb0 + lq * 4);
        gpre[1] = *(const uint2*)(gb + tb1 + lq * 4);
        gpre[2] = *(const uint2*)(gb + tb2 + lq * 4);
        gpre[3] = *(const uint2*)(gb + tb3 + lq * 4);
    } else {
#pragma unroll
        for (int kc = 0; kc < 4; ++kc)
            bx[kc] = *(const half8*)(xb + kc * 32 + lq * 8);
    }

    float c_reg[4] = {0.f, 0.f, 0.f, 0.f};
    _Float16* houtb = hout + (size_t)(r0 + lr) * L_ * H_ + 16 * w + lq * 4;
    __syncthreads();

    for (int t = 0; t < L_; ++t) {
        // h B-frags from LDS: col=lane&15 (row lr), k = kc*32 + lq*8 + e
        half8 bh[4];
#pragma unroll
        for (int kc = 0; kc < 4; ++kc)
            bh[kc] = *(const half8*)&hl[t & 1][lr][kc * 32 + lq * 8];

        f32x4 acc[4];
        if (MODE == 0) {
            acc[0] = cvt4h(gpre[0]); acc[1] = cvt4h(gpre[1]);
            acc[2] = cvt4h(gpre[2]); acc[3] = cvt4h(gpre[3]);
        } else {
            acc[0] = binit[0]; acc[1] = binit[1];
            acc[2] = binit[2]; acc[3] = binit[3];
        }

        int tn = (t < L_ - 1) ? t + 1 : t;
        uint2 gnx[4];
        if (MODE == 0) {
            const _Float16* gp = gb + (size_t)tn * G4;
            gnx[0] = *(const uint2*)(gp + tb0 + lq * 4);
            gnx[1] = *(const uint2*)(gp + tb1 + lq * 4);
            gnx[2] = *(const uint2*)(gp + tb2 + lq * 4);
            gnx[3] = *(const uint2*)(gp + tb3 + lq * 4);
        }

        if (MODE == 1) {
#pragma unroll
            for (int kc = 0; kc < 4; ++kc) {
                acc[0] = __builtin_amdgcn_mfma_f32_16x16x32_f16(aih[0][kc], bx[kc], acc[0], 0, 0, 0);
                acc[1] = __builtin_amdgcn_mfma_f32_16x16x32_f16(aih[1][kc], bx[kc], acc[1], 0, 0, 0);
                acc[2] = __builtin_amdgcn_mfma_f32_16x16x32_f16(aih[2][kc], bx[kc], acc[2], 0, 0, 0);
                acc[3] = __builtin_amdgcn_mfma_f32_16x16x32_f16(aih[3][kc], bx[kc], acc[3], 0, 0, 0);
            }
            // reload bx for t+1 (WAR after the ih-MFMAs consumed it)
            const _Float16* xp = xb + (size_t)tn * H_;
#pragma unroll
            for (int kc = 0; kc < 4; ++kc)
                bx[kc] = *(const half8*)(xp + kc * 32 + lq * 8);
        }
#pragma unroll
        for (int kc = 0; kc < 4; ++kc) {
            acc[0] = __builtin_amdgcn_mfma_f32_16x16x32_f16(ahh[0][kc], bh[kc], acc[0], 0, 0, 0);
            acc[1] = __builtin_amdgcn_mfma_f32_16x16x32_f16(ahh[1][kc], bh[kc], acc[1], 0, 0, 0);
            acc[2] = __builtin_amdgcn_mfma_f32_16x16x32_f16(ahh[2][kc], bh[kc], acc[2], 0, 0, 0);
            acc[3] = __builtin_amdgcn_mfma_f32_16x16x32_f16(ahh[3][kc], bh[kc], acc[3], 0, 0, 0);
        }

        // cell update: acc[0..3][j] = (i,f,g,o) of hd = 16w+lq*4+j, row = lr
        float hv[4];
#pragma unroll
        for (int j = 0; j < 4; ++j) {
            float c = sigm(acc[1][j]) * c_reg[j] + sigm(acc[0][j]) * tanh_f(acc[2][j]);
            hv[j] = sigm(acc[3][j]) * tanh_f(c);
            c_reg[j] = c;
        }
        uint2 hp2;
        hp2.x = packh(hv[0], hv[1]);
        hp2.y = packh(hv[2], hv[3]);
        *(uint2*)&hl[(t + 1) & 1][lr][16 * w + lq * 4] = hp2;
        *(uint2*)(houtb + (size_t)t * H_) = hp2;
        __syncthreads();
        if (MODE == 0) {
            gpre[0] = gnx[0]; gpre[1] = gnx[1];
            gpre[2] = gnx[2]; gpre[3] = gnx[3];
        }
    }
}

// ---------------------------------------------------------------------------
// kX2: fused epilogue.  afterx from h2 (f16 dot2), px/pt from etab+ttab.
// ---------------------------------------------------------------------------
__global__ void __launch_bounds__(256)
kX2(const int* __restrict__ x, const int* __restrict__ dpt,
    const int* __restrict__ adj, const __half* __restrict__ h2seq,
    const u32* __restrict__ wap, const float* __restrict__ bax,
    const float* __restrict__ etab, const float* __restrict__ ttab,
    float* __restrict__ pred_x, float* __restrict__ pred_t)
{
    __shared__ uint4 swp[512];
    __shared__ float stt[48 * 96];
    __shared__ float sbax[32];
    int tid = threadIdx.x;
    for (int i = tid; i < 512; i += 256) swp[i] = ((const uint4*)wap)[i];
    for (int i = tid; i < 4608; i += 256) stt[i] = ttab[i];
    if (tid < 32) sbax[tid] = bax[tid];
    __syncthreads();

    int bl = blockIdx.x * 256 + tid;
    int xt = x[bl], dt = dpt[bl];

    uint4 h2r[16];
    const uint4* h2p = (const uint4*)(h2seq + (size_t)bl * H_);
#pragma unroll
    for (int q = 0; q < 16; ++q) h2r[q] = h2p[q];

    float afterx[OD];
    for (int o = 0; o < OD; ++o) {
        float acc = sbax[o];
#pragma unroll
        for (int q = 0; q < 16; ++q) {
            uint4 w = swp[o * 16 + q];
            acc = dot2f(w.x, h2r[q].x, acc);
            acc = dot2f(w.y, h2r[q].y, acc);
            acc = dot2f(w.z, h2r[q].z, acc);
            acc = dot2f(w.w, h2r[q].w, acc);
        }
        afterx[o] = acc > 0.f ? acc : 0.f;
    }

    const float4* tp = (const float4*)(stt + dt * 96);
    float px[K_];
#pragma unroll
    for (int k = 0; k < K_; ++k) {
        int a = adj[xt * K_ + k];
        int ac = a < NE ? a : 0;
        const float4* ep = (const float4*)(etab + (size_t)ac * 96);
        float sx = 0.f, st = 0.f;
#pragma unroll
        for (int q = 0; q < 8; ++q) {
            float4 e = ep[q], tt = tp[q];
            sx += afterx[q * 4 + 0] * (e.x + tt.x)
                + afterx[q * 4 + 1] * (e.y + tt.y)
                + afterx[q * 4 + 2] * (e.z + tt.z)
                + afterx[q * 4 + 3] * (e.w + tt.w);
        }
#pragma unroll
        for (int q = 0; q < 8; ++q) {
            float4 em = ep[8 + q], tm = tp[8 + q];
            float4 ea = ep[16 + q], ta = tp[16 + q];
            float at0 = fmaxf(ea.x + ta.x, 0.f);
            float at1 = fmaxf(ea.y + ta.y, 0.f);
            float at2 = fmaxf(ea.z + ta.z, 0.f);
            float at3 = fmaxf(ea.w + ta.w, 0.f);
            st += at0 * (em.x + tm.x) + at1 * (em.y + tm.y)
                + at2 * (em.z + tm.z) + at3 * (em.w + tm.w);
        }
        px[k] = (a == NE) ? -INFINITY : sx;
        pred_t[(size_t)bl * K_ + k] = 1.f / (1.f + expf(-st));
    }

    float m = px[0];
#pragma unroll
    for (int k = 1; k < K_; ++k) m = fmaxf(m, px[k]);
    float ssum = 0.f;
#pragma unroll
    for (int k = 0; k < K_; ++k) ssum += expf(px[k] - m);
    float lse = logf(ssum) + m;
#pragma unroll
    for (int k = 0; k < K_; ++k)
        pred_x[(size_t)bl * K_ + k] = px[k] - lse;
}

// ---------------------------------------------------------------------------
extern "C" void kernel_launch(void* const* d_in, const int* in_sizes, int n_in,
                              void* d_out, int out_size, void* d_ws, size_t ws_size,
                              hipStream_t stream)
{
    (void)in_sizes; (void)n_in; (void)out_size; (void)ws_size;

    const int*   x      = (const int*)  d_in[0];
    const int*   dpt    = (const int*)  d_in[1];
    const float* z      = (const float*)d_in[2];
    const int*   adj    = (const int*)  d_in[3];
    const float* eprop  = (const float*)d_in[4];
    const float* x_emb  = (const float*)d_in[5];
    const float* t_emb  = (const float*)d_in[6];
    const float* tcost  = (const float*)d_in[7];
    const float* w_ih0  = (const float*)d_in[8];
    const float* w_hh0  = (const float*)d_in[9];
    const float* b_ih0  = (const float*)d_in[10];
    const float* b_hh0  = (const float*)d_in[11];
    const float* w_ih1  = (const float*)d_in[12];
    const float* w_hh1  = (const float*)d_in[13];
    const float* b_ih1  = (const float*)d_in[14];
    const float* b_hh1  = (const float*)d_in[15];
    const float* w_ih2  = (const float*)d_in[16];
    const float* w_hh2  = (const float*)d_in[17];
    const float* b_ih2  = (const float*)d_in[18];
    const float* b_hh2  = (const float*)d_in[19];
    const float* wax    = (const float*)d_in[20];
    const float* bax    = (const float*)d_in[21];
    const float* wat    = (const float*)d_in[22];
    const float* bat    = (const float*)d_in[23];
    const float* wmx    = (const float*)d_in[24];
    const float* bmx    = (const float*)d_in[25];
    const float* wmt    = (const float*)d_in[26];
    const float* bmt    = (const float*)d_in[27];

    float* out    = (float*)d_out;
    float* pred_x = out;
    float* pred_t = out + (size_t)B_ * L_ * K_;

    u32* wsu = (u32*)d_ws;
    u32* wih0p = wsu;                 // 49152
    u32* whh0  = wsu + 49152;
    u32* wih1p = wsu + 81920;
    u32* whh1  = wsu + 114688;
    u32* wih2p = wsu + 147456;
    u32* whh2  = wsu + 180224;
    u32* wap   = wsu + 212992;
    u32* wmxp  = wsu + 215040;
    u32* wmtp  = wsu + 217216;
    u32* watp0 = wsu + 219392;
    float* bsum = (float*)(wsu + 219904);          // [3][512]
    u32* A0    = wsu + 221440;                      // 65536*96
    _Float16* gin   = (_Float16*)(wsu + 6512896);   // 65536*512 f16
    _Float16* h0seq = (_Float16*)(wsu + 23290112);  // 65536*128 f16
    _Float16* h1seq = (_Float16*)(wsu + 27484416);
    _Float16* h2seq = (_Float16*)(wsu + 31678720);
    float* etab = (float*)(wsu + 35873024);         // 50000*96
    float* ttab = (float*)(wsu + 40673024);         // 4608

    kW2<<<865, 256, 0, stream>>>(w_ih0, w_hh0, w_ih1, w_hh1, w_ih2, w_hh2,
                                 wax, wmx, wmt, wat,
                                 b_ih0, b_hh0, b_ih1, b_hh1, b_ih2, b_hh2, wsu);

    kT<<<18, 256, 0, stream>>>(t_emb, wmx, wmt, wat, bmx, bmt, bat, ttab);

    kE<<<196, 256, 0, stream>>>(x_emb, eprop, tcost, wmxp, wmtp, watp0, etab);

    kAP<<<512, 512, 0, stream>>>(x, dpt, z, eprop, x_emb, t_emb, A0);

    kGm<6><<<1024, 512, 0, stream>>>((const _Float16*)A0, wih0p, bsum + 0, gin);

    kRecM<0><<<32, 512, 0, stream>>>(gin, nullptr, whh0, nullptr, nullptr, h0seq);
    kRecM<1><<<32, 512, 0, stream>>>(nullptr, h0seq, whh1, wih1p, bsum + 512, h1seq);
    kRecM<1><<<32, 512, 0, stream>>>(nullptr, h1seq, whh2, wih2p, bsum + 1024, h2seq);

    kX2<<<256, 256, 0, stream>>>(x, dpt, adj, (const __half*)h2seq, wap, bax,
                                 etab, ttab, pred_x, pred_t);
}

// Round 9
// 911.397 us; speedup vs baseline: 1.4134x; 1.4134x over previous
//
#include <hip/hip_runtime.h>
#include <hip/hip_fp16.h>
#include <math.h>
#include <stdint.h>

#define B_   512
#define L_   128
#define K_   9
#define NE   50000
#define ZD   16
#define TE   32
#define XE   128
#define EP   8
#define H_   128
#define G4   512
#define OD   32
#define IN0  184
#define MKD  168

typedef uint32_t u32;
typedef _Float16 half2v __attribute__((ext_vector_type(2)));
typedef _Float16 half8  __attribute__((ext_vector_type(8)));
typedef float    f32x4  __attribute__((ext_vector_type(4)));

__device__ __forceinline__ float sigm(float x) {
    x = fminf(fmaxf(x, -30.f), 30.f);
    return 1.f / (1.f + expf(-x));
}
__device__ __forceinline__ float tanh_f(float x) {
    x = fminf(fmaxf(x, -15.f), 15.f);
    float e = expf(2.f * x);
    return (e - 1.f) / (e + 1.f);
}
__device__ __forceinline__ float dot2f(u32 w, u32 h, float acc) {
#if __has_builtin(__builtin_amdgcn_fdot2)
    union { u32 u; half2v v; } a, b;
    a.u = w; b.u = h;
    return __builtin_amdgcn_fdot2(a.v, b.v, acc, false);
#else
    union { u32 u; __half2 h2; } a, b;
    a.u = w; b.u = h;
    float2 fa = __half22float2(a.h2), fb = __half22float2(b.h2);
    return fmaf(fa.x, fb.x, fmaf(fa.y, fb.y, acc));
#endif
}
__device__ __forceinline__ float dot4(uint4 w, uint4 h, float acc) {
    acc = dot2f(w.x, h.x, acc); acc = dot2f(w.y, h.y, acc);
    acc = dot2f(w.z, h.z, acc); acc = dot2f(w.w, h.w, acc);
    return acc;
}
__device__ __forceinline__ u32 packh(float lo, float hi) {
    union { __half2 h; u32 u; } p;
    p.h = __halves2half2(__float2half(lo), __float2half(hi));
    return p.u;
}
__device__ __forceinline__ f32x4 cvt4h(u32 a_, u32 b_) {
    union { u32 u; half2v v; } a, b;
    a.u = a_; b.u = b_;
    f32x4 r;
    r[0] = (float)a.v[0]; r[1] = (float)a.v[1];
    r[2] = (float)b.v[0]; r[3] = (float)b.v[1];
    return r;
}

// ---------------------------------------------------------------------------
// kW2: pack all weights (f16 pairs) + bias sums.
//   wih0p [512][96] row-major (K=192, cols 184..191 zero)  @ 0
//   whhQ0 [16 j4][512 g][4 q]  (col-quad layout for kRecL) @ 49152
//   wih1p [512][64] row-major                              @ 81920
//   whhQ1 [16][512][4]                                     @ 114688
//   wih2p [512][64] row-major                              @ 147456
//   whhQ2 [16][512][4]                                     @ 180224
//   wap   [32][64]                                         @ 212992
//   wmxp  [32][68]                                         @ 215040
//   wmtp  [32][68]                                         @ 217216
//   watp0 [32][16]                                         @ 219392
//   bsum  [3][512] f32                                     @ 219904
// whhQ: u32 index e -> q=e&3, g=(e>>2)&511, j4=e>>11, col-pair j2=4*j4+q.
// ---------------------------------------------------------------------------
__global__ void __launch_bounds__(256)
kW2(const float* __restrict__ w_ih0, const float* __restrict__ w_hh0,
    const float* __restrict__ w_ih1, const float* __restrict__ w_hh1,
    const float* __restrict__ w_ih2, const float* __restrict__ w_hh2,
    const float* __restrict__ wax, const float* __restrict__ wmx,
    const float* __restrict__ wmt, const float* __restrict__ wat,
    const float* __restrict__ b_ih0, const float* __restrict__ b_hh0,
    const float* __restrict__ b_ih1, const float* __restrict__ b_hh1,
    const float* __restrict__ b_ih2, const float* __restrict__ b_hh2,
    u32* __restrict__ wsu)
{
    int gid = blockIdx.x * 256 + threadIdx.x;
    if (gid < 49152) {
        int g = gid / 96, c = gid % 96;
        wsu[gid] = (c < 92) ? packh(w_ih0[g * IN0 + 2 * c], w_ih0[g * IN0 + 2 * c + 1]) : 0u;
    } else if (gid < 81920) {
        int e = gid - 49152;
        int q = e & 3, g = (e >> 2) & 511, j4 = e >> 11;
        int j2 = 4 * j4 + q;
        wsu[gid] = packh(w_hh0[g * H_ + 2 * j2], w_hh0[g * H_ + 2 * j2 + 1]);
    } else if (gid < 114688) {
        int e = gid - 81920; int g = e >> 6, c = e & 63;
        wsu[gid] = packh(w_ih1[g * H_ + 2 * c], w_ih1[g * H_ + 2 * c + 1]);
    } else if (gid < 147456) {
        int e = gid - 114688;
        int q = e & 3, g = (e >> 2) & 511, j4 = e >> 11;
        int j2 = 4 * j4 + q;
        wsu[gid] = packh(w_hh1[g * H_ + 2 * j2], w_hh1[g * H_ + 2 * j2 + 1]);
    } else if (gid < 180224) {
        int e = gid - 147456; int g = e >> 6, c = e & 63;
        wsu[gid] = packh(w_ih2[g * H_ + 2 * c], w_ih2[g * H_ + 2 * c + 1]);
    } else if (gid < 212992) {
        int e = gid - 180224;
        int q = e & 3, g = (e >> 2) & 511, j4 = e >> 11;
        int j2 = 4 * j4 + q;
        wsu[gid] = packh(w_hh2[g * H_ + 2 * j2], w_hh2[g * H_ + 2 * j2 + 1]);
    } else if (gid < 215040) {
        int e = gid - 212992; int o = e >> 6, c = e & 63;
        wsu[gid] = packh(wax[o * H_ + 2 * c], wax[o * H_ + 2 * c + 1]);
    } else if (gid < 217216) {
        int e = gid - 215040; int o = e / 68, c = e % 68;
        int col = c < 64 ? 2 * c : 160 + 2 * (c - 64);
        wsu[gid] = packh(wmx[o * MKD + col], wmx[o * MKD + col + 1]);
    } else if (gid < 219392) {
        int e = gid - 217216; int o = e / 68, c = e % 68;
        int col = c < 64 ? 2 * c : 160 + 2 * (c - 64);
        wsu[gid] = packh(wmt[o * MKD + col], wmt[o * MKD + col + 1]);
    } else if (gid < 219904) {
        int e = gid - 219392; int o = e >> 4, c = e & 15;
        wsu[gid] = packh(wat[o * 64 + 2 * c], wat[o * 64 + 2 * c + 1]);
    } else if (gid < 221440) {
        int e = gid - 219904; int layer = e >> 9, g = e & 511;
        float v;
        if (layer == 0)      v = b_ih0[g] + b_hh0[g];
        else if (layer == 1) v = b_ih1[g] + b_hh1[g];
        else                 v = b_ih2[g] + b_hh2[g];
        ((float*)wsu)[gid] = v;
    }
}

// ---------------------------------------------------------------------------
// kT: dt tables (48 x 96): [tmx(+bmx) | tmt(+bmt) | tat(+bat)]  (f32)
// ---------------------------------------------------------------------------
__global__ void __launch_bounds__(256)
kT(const float* __restrict__ t_emb,
   const float* __restrict__ wmx, const float* __restrict__ wmt,
   const float* __restrict__ wat,
   const float* __restrict__ bmx, const float* __restrict__ bmt,
   const float* __restrict__ bat, float* __restrict__ ttab)
{
    int gid = blockIdx.x * 256 + threadIdx.x;
    if (gid >= 48 * 96) return;
    int dt = gid / 96, o96 = gid % 96;
    const float* te = t_emb + dt * TE;
    int o = o96 & 31;
    float acc;
    const float* w;
    if (o96 < 32)      { acc = bmx[o]; w = wmx + o * MKD + XE; }
    else if (o96 < 64) { acc = bmt[o]; w = wmt + o * MKD + XE; }
    else               { acc = bat[o]; w = wat + o * 64 + TE; }
    for (int d = 0; d < TE; ++d) acc = fmaf(te[d], w[d], acc);
    ttab[dt * 96 + o96] = acc;
}

// ---------------------------------------------------------------------------
// kE: per-edge tables (50000 x 96, f16): [emx | emt | eat]  (no biases)
// ---------------------------------------------------------------------------
__global__ void __launch_bounds__(256)
kE(const float* __restrict__ x_emb, const float* __restrict__ eprop,
   const float* __restrict__ tcost,
   const u32* __restrict__ wmxp, const u32* __restrict__ wmtp,
   const u32* __restrict__ watp0, _Float16* __restrict__ etab)
{
    __shared__ uint4 smx[544], smt[544], sat[128];
    int tid = threadIdx.x;
    for (int i = tid; i < 544; i += 256) {
        smx[i] = ((const uint4*)wmxp)[i];
        smt[i] = ((const uint4*)wmtp)[i];
    }
    if (tid < 128) sat[tid] = ((const uint4*)watp0)[tid];
    __syncthreads();
    int e = blockIdx.x * 256 + tid;
    if (e >= NE) return;

    u32 in[68], tin[16];
    const float* xr = x_emb + (size_t)e * XE;
#pragma unroll
    for (int c = 0; c < 64; ++c) in[c] = packh(xr[2 * c], xr[2 * c + 1]);
    const float* er = eprop + (size_t)e * EP;
#pragma unroll
    for (int c = 0; c < 4; ++c) in[64 + c] = packh(er[2 * c], er[2 * c + 1]);
    const float* tr = tcost + (size_t)e * TE;
#pragma unroll
    for (int c = 0; c < 16; ++c) tin[c] = packh(tr[2 * c], tr[2 * c + 1]);

    _Float16* outp = etab + (size_t)e * 96;
    for (int o = 0; o < OD; ++o) {
        float ax = 0.f, am = 0.f, aa = 0.f;
#pragma unroll
        for (int c4 = 0; c4 < 17; ++c4) {
            uint4 wx = smx[o * 17 + c4], wt = smt[o * 17 + c4];
            ax = dot2f(wx.x, in[c4 * 4 + 0], ax);
            ax = dot2f(wx.y, in[c4 * 4 + 1], ax);
            ax = dot2f(wx.z, in[c4 * 4 + 2], ax);
            ax = dot2f(wx.w, in[c4 * 4 + 3], ax);
            am = dot2f(wt.x, in[c4 * 4 + 0], am);
            am = dot2f(wt.y, in[c4 * 4 + 1], am);
            am = dot2f(wt.z, in[c4 * 4 + 2], am);
            am = dot2f(wt.w, in[c4 * 4 + 3], am);
        }
#pragma unroll
        for (int c4 = 0; c4 < 4; ++c4) {
            uint4 wa = sat[o * 4 + c4];
            aa = dot2f(wa.x, tin[c4 * 4 + 0], aa);
            aa = dot2f(wa.y, tin[c4 * 4 + 1], aa);
            aa = dot2f(wa.z, tin[c4 * 4 + 2], aa);
            aa = dot2f(wa.w, tin[c4 * 4 + 3], aa);
        }
        outp[o] = (_Float16)ax;
        outp[32 + o] = (_Float16)am;
        outp[64 + o] = (_Float16)aa;
    }
}

// ---------------------------------------------------------------------------
// kAP: build layer-0 A panel [65536][96 u32] (K=192, pad 184..191 = 0)
// ---------------------------------------------------------------------------
__global__ void __launch_bounds__(512)
kAP(const int* __restrict__ x, const int* __restrict__ dpt,
    const float* __restrict__ z, const float* __restrict__ eprop,
    const float* __restrict__ x_emb, const float* __restrict__ t_emb,
    u32* __restrict__ A0)
{
    int tid = threadIdx.x;
    int i = tid >> 2, q = tid & 3;
    int bl = blockIdx.x * 128 + i;
    int xt = x[bl], dt = dpt[bl];
    int b = bl >> 7, l = bl & 127;
    const float* zr = z + ((size_t)l * B_ + b) * ZD;
    const float* xr = x_emb + (size_t)xt * XE;
    const float* tr = t_emb + (size_t)dt * TE;
    const float* er = eprop + (size_t)xt * EP;
    u32* outp = A0 + (size_t)bl * 96;
#pragma unroll
    for (int cc = 0; cc < 24; ++cc) {
        int c = q * 24 + cc;
        float lo, hi;
        if (c < 8)       { lo = zr[2 * c];          hi = zr[2 * c + 1]; }
        else if (c < 72) { lo = xr[2 * (c - 8)];    hi = xr[2 * (c - 8) + 1]; }
        else if (c < 88) { lo = tr[2 * (c - 72)];   hi = tr[2 * (c - 72) + 1]; }
        else if (c < 92) { lo = er[2 * (c - 88)];   hi = er[2 * (c - 88) + 1]; }
        else             { lo = 0.f;                hi = 0.f; }
        outp[c] = packh(lo, hi);
    }
}

// ---------------------------------------------------------------------------
// kGm<KC>: MFMA GEMM.  Out[M][512] (f16) = A[M][KC*32] @ W[512][KC*32]^T + bsum.
// ---------------------------------------------------------------------------
template<int KC>
__global__ void __launch_bounds__(512, 2)
kGm(const _Float16* __restrict__ A, const u32* __restrict__ Wp,
    const float* __restrict__ bsum, _Float16* __restrict__ Out)
{
    const int K = KC * 32;
    int tid = threadIdx.x;
    int w = tid >> 6, l = tid & 63;
    int lr = l & 15, lq = l >> 4;
    int bl0 = blockIdx.x * 64;

    half8 a[4][KC];
#pragma unroll
    for (int t = 0; t < 4; ++t)
#pragma unroll
        for (int c = 0; c < KC; ++c)
            a[t][c] = *reinterpret_cast<const half8*>(
                A + (size_t)(bl0 + t * 16 + lr) * K + c * 32 + lq * 8);

#pragma unroll
    for (int pass = 0; pass < 4; ++pass) {
        int g = pass * 128 + w * 16 + lr;
        half8 bfr[KC];
#pragma unroll
        for (int c = 0; c < KC; ++c)
            bfr[c] = *reinterpret_cast<const half8*>(
                (const _Float16*)Wp + (size_t)g * K + c * 32 + lq * 8);
        float bias = bsum[g];
#pragma unroll
        for (int t = 0; t < 4; ++t) {
            f32x4 acc = {0.f, 0.f, 0.f, 0.f};
#pragma unroll
            for (int c = 0; c < KC; ++c)
                acc = __builtin_amdgcn_mfma_f32_16x16x32_f16(a[t][c], bfr[c], acc, 0, 0, 0);
#pragma unroll
            for (int j = 0; j < 4; ++j) {
                int item = bl0 + t * 16 + lq * 4 + j;
                Out[(size_t)item * G4 + g] = (_Float16)(acc[j] + bias);
            }
        }
    }
}

// ---------------------------------------------------------------------------
// kRecL: serial LSTM recurrence with W_hh resident in LDS (128 KB).
// 256 blocks (1/CU) x 512 threads; block owns 2 batch rows; thread = gate.
// Weight layout [j4][512][4] -> per-step reads are conflict-free ds_read_b128
// (lane g -> consecutive 16B).  h packed f16 read as broadcast b128.
// Only ~48 VGPR live -> nothing for the allocator to spill (rounds 4-8 all
// died on VGPR-residency of weights; LDS sidesteps it).
// ---------------------------------------------------------------------------
__global__ void __launch_bounds__(512, 1)
kRecL(const _Float16* __restrict__ gin, const uint4* __restrict__ whQ,
      _Float16* __restrict__ hout)
{
    __shared__ uint4 wlds[16 * 512];     // 128 KB
    __shared__ float sg[2][G4];          // 4 KB
    __shared__ u32 hb[2][64];            // 512 B packed h
    const int g  = threadIdx.x;          // gate 0..511
    const int b0 = blockIdx.x * 2;

    for (int i = g; i < 16 * 512; i += 512) wlds[i] = whQ[i];
    if (g < 128) ((u32*)hb)[g] = 0;

    const int r_ = g >> 7, hd_ = g & 127;
    float c_reg = 0.f;
    const _Float16* gb0 = gin + (size_t)(b0 + 0) * L_ * G4 + g;
    const _Float16* gb1 = gin + (size_t)(b0 + 1) * L_ * G4 + g;
    float p0 = (float)*gb0, p1 = (float)*gb1;
    __syncthreads();

    for (int l = 0; l < L_; ++l) {
        int ln = (l < L_ - 1) ? l + 1 : l;
        float n0 = (float)gb0[(size_t)ln * G4];
        float n1 = (float)gb1[(size_t)ln * G4];
        float a0 = p0, a1 = p1;
        const uint4* h0q = (const uint4*)hb[0];
        const uint4* h1q = (const uint4*)hb[1];
#pragma unroll
        for (int j4 = 0; j4 < 16; ++j4) {
            uint4 wq  = wlds[j4 * 512 + g];
            uint4 hq0 = h0q[j4];
            uint4 hq1 = h1q[j4];
            a0 = dot4(wq, hq0, a0);
            a1 = dot4(wq, hq1, a1);
        }
        sg[0][g] = a0; sg[1][g] = a1;
        __syncthreads();
        if (g < 256) {
            float gi = sg[r_][hd_], gf = sg[r_][H_ + hd_];
            float gg = sg[r_][2 * H_ + hd_], go = sg[r_][3 * H_ + hd_];
            float c = sigm(gf) * c_reg + sigm(gi) * tanh_f(gg);
            float h = sigm(go) * tanh_f(c);
            c_reg = c;
            _Float16 hh = (_Float16)h;
            ((_Float16*)hb[r_])[hd_] = hh;
            hout[((size_t)(b0 + r_) * L_ + l) * H_ + hd_] = hh;
        }
        __syncthreads();
        p0 = n0; p1 = n1;
    }
}

// ---------------------------------------------------------------------------
// kX2: fused epilogue.  afterx from h2 (f16 dot2), px/pt from etab(f16)+ttab.
// ---------------------------------------------------------------------------
__global__ void __launch_bounds__(256)
kX2(const int* __restrict__ x, const int* __restrict__ dpt,
    const int* __restrict__ adj, const __half* __restrict__ h2seq,
    const u32* __restrict__ wap, const float* __restrict__ bax,
    const _Float16* __restrict__ etab, const float* __restrict__ ttab,
    float* __restrict__ pred_x, float* __restrict__ pred_t)
{
    __shared__ uint4 swp[512];
    __shared__ float stt[48 * 96];
    __shared__ float sbax[32];
    int tid = threadIdx.x;
    for (int i = tid; i < 512; i += 256) swp[i] = ((const uint4*)wap)[i];
    for (int i = tid; i < 4608; i += 256) stt[i] = ttab[i];
    if (tid < 32) sbax[tid] = bax[tid];
    __syncthreads();

    int bl = blockIdx.x * 256 + tid;
    int xt = x[bl], dt = dpt[bl];

    uint4 h2r[16];
    const uint4* h2p = (const uint4*)(h2seq + (size_t)bl * H_);
#pragma unroll
    for (int q = 0; q < 16; ++q) h2r[q] = h2p[q];

    float afterx[OD];
    for (int o = 0; o < OD; ++o) {
        float acc = sbax[o];
#pragma unroll
        for (int q = 0; q < 16; ++q) {
            uint4 w = swp[o * 16 + q];
            acc = dot2f(w.x, h2r[q].x, acc);
            acc = dot2f(w.y, h2r[q].y, acc);
            acc = dot2f(w.z, h2r[q].z, acc);
            acc = dot2f(w.w, h2r[q].w, acc);
        }
        afterx[o] = acc > 0.f ? acc : 0.f;
    }

    const float* tB = stt + dt * 96;
    float px[K_];
#pragma unroll
    for (int k = 0; k < K_; ++k) {
        int a = adj[xt * K_ + k];
        int ac = a < NE ? a : 0;
        const uint4* ep = (const uint4*)(etab + (size_t)ac * 96);  // 12 uint4
        float sx = 0.f, st = 0.f;
#pragma unroll
        for (int q = 0; q < 4; ++q) {
            uint4 e = ep[q];
            f32x4 e0 = cvt4h(e.x, e.y);
            f32x4 e1 = cvt4h(e.z, e.w);
#pragma unroll
            for (int j = 0; j < 4; ++j) {
                sx += afterx[q * 8 + j]     * (e0[j] + tB[q * 8 + j]);
                sx += afterx[q * 8 + 4 + j] * (e1[j] + tB[q * 8 + 4 + j]);
            }
        }
#pragma unroll
        for (int q = 0; q < 4; ++q) {
            uint4 em4 = ep[4 + q], ea4 = ep[8 + q];
            f32x4 m0 = cvt4h(em4.x, em4.y), m1 = cvt4h(em4.z, em4.w);
            f32x4 a0 = cvt4h(ea4.x, ea4.y), a1 = cvt4h(ea4.z, ea4.w);
#pragma unroll
            for (int j = 0; j < 4; ++j) {
                float at0 = fmaxf(a0[j] + tB[64 + q * 8 + j], 0.f);
                float at1 = fmaxf(a1[j] + tB[64 + q * 8 + 4 + j], 0.f);
                st += at0 * (m0[j] + tB[32 + q * 8 + j]);
                st += at1 * (m1[j] + tB[32 + q * 8 + 4 + j]);
            }
        }
        px[k] = (a == NE) ? -INFINITY : sx;
        pred_t[(size_t)bl * K_ + k] = 1.f / (1.f + expf(-st));
    }

    float m = px[0];
#pragma unroll
    for (int k = 1; k < K_; ++k) m = fmaxf(m, px[k]);
    float ssum = 0.f;
#pragma unroll
    for (int k = 0; k < K_; ++k) ssum += expf(px[k] - m);
    float lse = logf(ssum) + m;
#pragma unroll
    for (int k = 0; k < K_; ++k)
        pred_x[(size_t)bl * K_ + k] = px[k] - lse;
}

// ---------------------------------------------------------------------------
extern "C" void kernel_launch(void* const* d_in, const int* in_sizes, int n_in,
                              void* d_out, int out_size, void* d_ws, size_t ws_size,
                              hipStream_t stream)
{
    (void)in_sizes; (void)n_in; (void)out_size; (void)ws_size;

    const int*   x      = (const int*)  d_in[0];
    const int*   dpt    = (const int*)  d_in[1];
    const float* z      = (const float*)d_in[2];
    const int*   adj    = (const int*)  d_in[3];
    const float* eprop  = (const float*)d_in[4];
    const float* x_emb  = (const float*)d_in[5];
    const float* t_emb  = (const float*)d_in[6];
    const float* tcost  = (const float*)d_in[7];
    const float* w_ih0  = (const float*)d_in[8];
    const float* w_hh0  = (const float*)d_in[9];
    const float* b_ih0  = (const float*)d_in[10];
    const float* b_hh0  = (const float*)d_in[11];
    const float* w_ih1  = (const float*)d_in[12];
    const float* w_hh1  = (const float*)d_in[13];
    const float* b_ih1  = (const float*)d_in[14];
    const float* b_hh1  = (const float*)d_in[15];
    const float* w_ih2  = (const float*)d_in[16];
    const float* w_hh2  = (const float*)d_in[17];
    const float* b_ih2  = (const float*)d_in[18];
    const float* b_hh2  = (const float*)d_in[19];
    const float* wax    = (const float*)d_in[20];
    const float* bax    = (const float*)d_in[21];
    const float* wat    = (const float*)d_in[22];
    const float* bat    = (const float*)d_in[23];
    const float* wmx    = (const float*)d_in[24];
    const float* bmx    = (const float*)d_in[25];
    const float* wmt    = (const float*)d_in[26];
    const float* bmt    = (const float*)d_in[27];

    float* out    = (float*)d_out;
    float* pred_x = out;
    float* pred_t = out + (size_t)B_ * L_ * K_;

    u32* wsu = (u32*)d_ws;
    u32* wih0p = wsu;                 // 49152
    u32* whhQ0 = wsu + 49152;
    u32* wih1p = wsu + 81920;
    u32* whhQ1 = wsu + 114688;
    u32* wih2p = wsu + 147456;
    u32* whhQ2 = wsu + 180224;
    u32* wap   = wsu + 212992;
    u32* wmxp  = wsu + 215040;
    u32* wmtp  = wsu + 217216;
    u32* watp0 = wsu + 219392;
    float* bsum = (float*)(wsu + 219904);           // [3][512]
    u32* A0    = wsu + 221440;                      // 65536*96
    _Float16* gin   = (_Float16*)(wsu + 6512896);   // 65536*512 f16
    _Float16* h0seq = (_Float16*)(wsu + 23290112);  // 65536*128 f16
    _Float16* h1seq = (_Float16*)(wsu + 27484416);
    _Float16* h2seq = (_Float16*)(wsu + 31678720);
    _Float16* etab  = (_Float16*)(wsu + 35873024);  // 50000*96 f16
    float* ttab = (float*)(wsu + 40673024);         // 4608

    kW2<<<865, 256, 0, stream>>>(w_ih0, w_hh0, w_ih1, w_hh1, w_ih2, w_hh2,
                                 wax, wmx, wmt, wat,
                                 b_ih0, b_hh0, b_ih1, b_hh1, b_ih2, b_hh2, wsu);

    kT<<<18, 256, 0, stream>>>(t_emb, wmx, wmt, wat, bmx, bmt, bat, ttab);

    kE<<<196, 256, 0, stream>>>(x_emb, eprop, tcost, wmxp, wmtp, watp0, etab);

    kAP<<<512, 512, 0, stream>>>(x, dpt, z, eprop, x_emb, t_emb, A0);

    kGm<6><<<1024, 512, 0, stream>>>((const _Float16*)A0, wih0p, bsum + 0, gin);
    kRecL<<<256, 512, 0, stream>>>(gin, (const uint4*)whhQ0, h0seq);

    kGm<4><<<1024, 512, 0, stream>>>(h0seq, wih1p, bsum + 512, gin);
    kRecL<<<256, 512, 0, stream>>>(gin, (const uint4*)whhQ1, h1seq);

    kGm<4><<<1024, 512, 0, stream>>>(h1seq, wih2p, bsum + 1024, gin);
    kRecL<<<256, 512, 0, stream>>>(gin, (const uint4*)whhQ2, h2seq);

    kX2<<<256, 256, 0, stream>>>(x, dpt, adj, (const __half*)h2seq, wap, bax,
                                 etab, ttab, pred_x, pred_t);
}

// Round 11
// 787.645 us; speedup vs baseline: 1.6355x; 1.1571x over previous
//
#include <hip/hip_runtime.h>
#include <hip/hip_fp16.h>
#include <math.h>
#include <stdint.h>

#define B_   512
#define L_   128
#define K_   9
#define NE   50000
#define ZD   16
#define TE   32
#define XE   128
#define EP   8
#define H_   128
#define G4   512
#define OD   32
#define IN0  184
#define MKD  168

typedef uint32_t u32;
typedef _Float16 half2v __attribute__((ext_vector_type(2)));
typedef _Float16 half8  __attribute__((ext_vector_type(8)));
typedef float    f32x4  __attribute__((ext_vector_type(4)));

__device__ __forceinline__ float sigm(float x) {
    x = fminf(fmaxf(x, -30.f), 30.f);
    return 1.f / (1.f + expf(-x));
}
__device__ __forceinline__ float tanh_f(float x) {
    x = fminf(fmaxf(x, -15.f), 15.f);
    float e = expf(2.f * x);
    return (e - 1.f) / (e + 1.f);
}
__device__ __forceinline__ float dot2f(u32 w, u32 h, float acc) {
#if __has_builtin(__builtin_amdgcn_fdot2)
    union { u32 u; half2v v; } a, b;
    a.u = w; b.u = h;
    return __builtin_amdgcn_fdot2(a.v, b.v, acc, false);
#else
    union { u32 u; __half2 h2; } a, b;
    a.u = w; b.u = h;
    float2 fa = __half22float2(a.h2), fb = __half22float2(b.h2);
    return fmaf(fa.x, fb.x, fmaf(fa.y, fb.y, acc));
#endif
}
__device__ __forceinline__ int sdot4i(u32 a, u32 b, int c) {
#if __has_builtin(__builtin_amdgcn_sdot4)
    return __builtin_amdgcn_sdot4((int)a, (int)b, c, false);
#else
    int r = c;
#pragma unroll
    for (int k = 0; k < 4; ++k) {
        int av = (int)(signed char)(a >> (8 * k));
        int bv = (int)(signed char)(b >> (8 * k));
        r += av * bv;
    }
    return r;
#endif
}
__device__ __forceinline__ u32 packh(float lo, float hi) {
    union { __half2 h; u32 u; } p;
    p.h = __halves2half2(__float2half(lo), __float2half(hi));
    return p.u;
}
__device__ __forceinline__ f32x4 cvt4h(u32 a_, u32 b_) {
    union { u32 u; half2v v; } a, b;
    a.u = a_; b.u = b_;
    f32x4 r;
    r[0] = (float)a.v[0]; r[1] = (float)a.v[1];
    r[2] = (float)b.v[0]; r[3] = (float)b.v[1];
    return r;
}

// ---------------------------------------------------------------------------
// kW2: pack weights (f16 pairs) + bias sums.  (whhQ* f16 regions are later
// overwritten by kQ's int8 tables — kept to minimize diff.)
// ---------------------------------------------------------------------------
__global__ void __launch_bounds__(256)
kW2(const float* __restrict__ w_ih0, const float* __restrict__ w_hh0,
    const float* __restrict__ w_ih1, const float* __restrict__ w_hh1,
    const float* __restrict__ w_ih2, const float* __restrict__ w_hh2,
    const float* __restrict__ wax, const float* __restrict__ wmx,
    const float* __restrict__ wmt, const float* __restrict__ wat,
    const float* __restrict__ b_ih0, const float* __restrict__ b_hh0,
    const float* __restrict__ b_ih1, const float* __restrict__ b_hh1,
    const float* __restrict__ b_ih2, const float* __restrict__ b_hh2,
    u32* __restrict__ wsu)
{
    int gid = blockIdx.x * 256 + threadIdx.x;
    if (gid < 49152) {
        int g = gid / 96, c = gid % 96;
        wsu[gid] = (c < 92) ? packh(w_ih0[g * IN0 + 2 * c], w_ih0[g * IN0 + 2 * c + 1]) : 0u;
    } else if (gid < 81920) {
        // dead region (int8 kQ overwrites)
    } else if (gid < 114688) {
        int e = gid - 81920; int g = e >> 6, c = e & 63;
        wsu[gid] = packh(w_ih1[g * H_ + 2 * c], w_ih1[g * H_ + 2 * c + 1]);
    } else if (gid < 147456) {
        // dead region
    } else if (gid < 180224) {
        int e = gid - 147456; int g = e >> 6, c = e & 63;
        wsu[gid] = packh(w_ih2[g * H_ + 2 * c], w_ih2[g * H_ + 2 * c + 1]);
    } else if (gid < 212992) {
        // dead region
    } else if (gid < 215040) {
        int e = gid - 212992; int o = e >> 6, c = e & 63;
        wsu[gid] = packh(wax[o * H_ + 2 * c], wax[o * H_ + 2 * c + 1]);
    } else if (gid < 217216) {
        int e = gid - 215040; int o = e / 68, c = e % 68;
        int col = c < 64 ? 2 * c : 160 + 2 * (c - 64);
        wsu[gid] = packh(wmx[o * MKD + col], wmx[o * MKD + col + 1]);
    } else if (gid < 219392) {
        int e = gid - 217216; int o = e / 68, c = e % 68;
        int col = c < 64 ? 2 * c : 160 + 2 * (c - 64);
        wsu[gid] = packh(wmt[o * MKD + col], wmt[o * MKD + col + 1]);
    } else if (gid < 219904) {
        int e = gid - 219392; int o = e >> 4, c = e & 15;
        wsu[gid] = packh(wat[o * 64 + 2 * c], wat[o * 64 + 2 * c + 1]);
    } else if (gid < 221440) {
        int e = gid - 219904; int layer = e >> 9, g = e & 511;
        float v;
        if (layer == 0)      v = b_ih0[g] + b_hh0[g];
        else if (layer == 1) v = b_ih1[g] + b_hh1[g];
        else                 v = b_ih2[g] + b_hh2[g];
        ((float*)wsu)[gid] = v;
    }
}

// ---------------------------------------------------------------------------
// kQ: int8-quantize W_hh per gate row.  Layer l tables at u32 offset
// {49152,114688,180224}: qw [8 j8][512 g][4 u32] (16 int8 cols per uint4),
// then msc[512] f32 at base+16384.  gate_hh = msc[g] * sdot4(qw, qh).
// ---------------------------------------------------------------------------
__global__ void __launch_bounds__(256)
kQ(const float* __restrict__ w_hh0, const float* __restrict__ w_hh1,
   const float* __restrict__ w_hh2, u32* __restrict__ wsu)
{
    int gid = blockIdx.x * 256 + threadIdx.x;
    if (gid >= 1536) return;
    int layer = gid >> 9, g = gid & 511;
    const int baseoff[3] = {49152, 114688, 180224};
    const float* src = (layer == 0 ? w_hh0 : layer == 1 ? w_hh1 : w_hh2) + (size_t)g * H_;
    float amax = 1e-20f;
    for (int k = 0; k < H_; ++k) amax = fmaxf(amax, fabsf(src[k]));
    float inv = 127.f / amax;
    u32* qw = wsu + baseoff[layer];
    float* msc = (float*)(wsu + baseoff[layer] + 16384);
    msc[g] = amax / (127.f * 127.f);
#pragma unroll
    for (int j8 = 0; j8 < 8; ++j8) {
#pragma unroll
        for (int q = 0; q < 4; ++q) {
            u32 word = 0;
#pragma unroll
            for (int b = 0; b < 4; ++b) {
                int col = j8 * 16 + q * 4 + b;
                int v = (int)rintf(src[col] * inv);
                v = v > 127 ? 127 : (v < -127 ? -127 : v);
                word |= ((u32)(v & 0xff)) << (8 * b);
            }
            qw[(j8 * 512 + g) * 4 + q] = word;
        }
    }
}

// ---------------------------------------------------------------------------
// kT: dt tables (48 x 96): [tmx(+bmx) | tmt(+bmt) | tat(+bat)]  (f32)
// ---------------------------------------------------------------------------
__global__ void __launch_bounds__(256)
kT(const float* __restrict__ t_emb,
   const float* __restrict__ wmx, const float* __restrict__ wmt,
   const float* __restrict__ wat,
   const float* __restrict__ bmx, const float* __restrict__ bmt,
   const float* __restrict__ bat, float* __restrict__ ttab)
{
    int gid = blockIdx.x * 256 + threadIdx.x;
    if (gid >= 48 * 96) return;
    int dt = gid / 96, o96 = gid % 96;
    const float* te = t_emb + dt * TE;
    int o = o96 & 31;
    float acc;
    const float* w;
    if (o96 < 32)      { acc = bmx[o]; w = wmx + o * MKD + XE; }
    else if (o96 < 64) { acc = bmt[o]; w = wmt + o * MKD + XE; }
    else               { acc = bat[o]; w = wat + o * 64 + TE; }
    for (int d = 0; d < TE; ++d) acc = fmaf(te[d], w[d], acc);
    ttab[dt * 96 + o96] = acc;
}

// ---------------------------------------------------------------------------
// kE: per-edge tables (50000 x 96, f16): [emx | emt | eat]  (no biases)
// ---------------------------------------------------------------------------
__global__ void __launch_bounds__(256)
kE(const float* __restrict__ x_emb, const float* __restrict__ eprop,
   const float* __restrict__ tcost,
   const u32* __restrict__ wmxp, const u32* __restrict__ wmtp,
   const u32* __restrict__ watp0, _Float16* __restrict__ etab)
{
    __shared__ uint4 smx[544], smt[544], sat[128];
    int tid = threadIdx.x;
    for (int i = tid; i < 544; i += 256) {
        smx[i] = ((const uint4*)wmxp)[i];
        smt[i] = ((const uint4*)wmtp)[i];
    }
    if (tid < 128) sat[tid] = ((const uint4*)watp0)[tid];
    __syncthreads();
    int e = blockIdx.x * 256 + tid;
    if (e >= NE) return;

    u32 in[68], tin[16];
    const float* xr = x_emb + (size_t)e * XE;
#pragma unroll
    for (int c = 0; c < 64; ++c) in[c] = packh(xr[2 * c], xr[2 * c + 1]);
    const float* er = eprop + (size_t)e * EP;
#pragma unroll
    for (int c = 0; c < 4; ++c) in[64 + c] = packh(er[2 * c], er[2 * c + 1]);
    const float* tr = tcost + (size_t)e * TE;
#pragma unroll
    for (int c = 0; c < 16; ++c) tin[c] = packh(tr[2 * c], tr[2 * c + 1]);

    _Float16* outp = etab + (size_t)e * 96;
    for (int o = 0; o < OD; ++o) {
        float ax = 0.f, am = 0.f, aa = 0.f;
#pragma unroll
        for (int c4 = 0; c4 < 17; ++c4) {
            uint4 wx = smx[o * 17 + c4], wt = smt[o * 17 + c4];
            ax = dot2f(wx.x, in[c4 * 4 + 0], ax);
            ax = dot2f(wx.y, in[c4 * 4 + 1], ax);
            ax = dot2f(wx.z, in[c4 * 4 + 2], ax);
            ax = dot2f(wx.w, in[c4 * 4 + 3], ax);
            am = dot2f(wt.x, in[c4 * 4 + 0], am);
            am = dot2f(wt.y, in[c4 * 4 + 1], am);
            am = dot2f(wt.z, in[c4 * 4 + 2], am);
            am = dot2f(wt.w, in[c4 * 4 + 3], am);
        }
#pragma unroll
        for (int c4 = 0; c4 < 4; ++c4) {
            uint4 wa = sat[o * 4 + c4];
            aa = dot2f(wa.x, tin[c4 * 4 + 0], aa);
            aa = dot2f(wa.y, tin[c4 * 4 + 1], aa);
            aa = dot2f(wa.z, tin[c4 * 4 + 2], aa);
            aa = dot2f(wa.w, tin[c4 * 4 + 3], aa);
        }
        outp[o] = (_Float16)ax;
        outp[32 + o] = (_Float16)am;
        outp[64 + o] = (_Float16)aa;
    }
}

// ---------------------------------------------------------------------------
// kAP: build layer-0 A panel [65536][96 u32] (K=192, pad 184..191 = 0)
// ---------------------------------------------------------------------------
__global__ void __launch_bounds__(512)
kAP(const int* __restrict__ x, const int* __restrict__ dpt,
    const float* __restrict__ z, const float* __restrict__ eprop,
    const float* __restrict__ x_emb, const float* __restrict__ t_emb,
    u32* __restrict__ A0)
{
    int tid = threadIdx.x;
    int i = tid >> 2, q = tid & 3;
    int bl = blockIdx.x * 128 + i;
    int xt = x[bl], dt = dpt[bl];
    int b = bl >> 7, l = bl & 127;
    const float* zr = z + ((size_t)l * B_ + b) * ZD;
    const float* xr = x_emb + (size_t)xt * XE;
    const float* tr = t_emb + (size_t)dt * TE;
    const float* er = eprop + (size_t)xt * EP;
    u32* outp = A0 + (size_t)bl * 96;
#pragma unroll
    for (int cc = 0; cc < 24; ++cc) {
        int c = q * 24 + cc;
        float lo, hi;
        if (c < 8)       { lo = zr[2 * c];          hi = zr[2 * c + 1]; }
        else if (c < 72) { lo = xr[2 * (c - 8)];    hi = xr[2 * (c - 8) + 1]; }
        else if (c < 88) { lo = tr[2 * (c - 72)];   hi = tr[2 * (c - 72) + 1]; }
        else if (c < 92) { lo = er[2 * (c - 88)];   hi = er[2 * (c - 88) + 1]; }
        else             { lo = 0.f;                hi = 0.f; }
        outp[c] = packh(lo, hi);
    }
}

// ---------------------------------------------------------------------------
// kGm<KC>: MFMA GEMM.  Out[M][512] (f16) = A[M][KC*32] @ W[512][KC*32]^T + bsum.
// ---------------------------------------------------------------------------
template<int KC>
__global__ void __launch_bounds__(512, 2)
kGm(const _Float16* __restrict__ A, const u32* __restrict__ Wp,
    const float* __restrict__ bsum, _Float16* __restrict__ Out)
{
    const int K = KC * 32;
    int tid = threadIdx.x;
    int w = tid >> 6, l = tid & 63;
    int lr = l & 15, lq = l >> 4;
    int bl0 = blockIdx.x * 64;

    half8 a[4][KC];
#pragma unroll
    for (int t = 0; t < 4; ++t)
#pragma unroll
        for (int c = 0; c < KC; ++c)
            a[t][c] = *reinterpret_cast<const half8*>(
                A + (size_t)(bl0 + t * 16 + lr) * K + c * 32 + lq * 8);

#pragma unroll
    for (int pass = 0; pass < 4; ++pass) {
        int g = pass * 128 + w * 16 + lr;
        half8 bfr[KC];
#pragma unroll
        for (int c = 0; c < KC; ++c)
            bfr[c] = *reinterpret_cast<const half8*>(
                (const _Float16*)Wp + (size_t)g * K + c * 32 + lq * 8);
        float bias = bsum[g];
#pragma unroll
        for (int t = 0; t < 4; ++t) {
            f32x4 acc = {0.f, 0.f, 0.f, 0.f};
#pragma unroll
            for (int c = 0; c < KC; ++c)
                acc = __builtin_amdgcn_mfma_f32_16x16x32_f16(a[t][c], bfr[c], acc, 0, 0, 0);
#pragma unroll
            for (int j = 0; j < 4; ++j) {
                int item = bl0 + t * 16 + lq * 4 + j;
                Out[(size_t)item * G4 + g] = (_Float16)(acc[j] + bias);
            }
        }
    }
}

// ---------------------------------------------------------------------------
// kRecL8: serial LSTM recurrence, int8 weights in LDS (64 KB) + int8 h.
// 256 blocks x 512 threads; 2 rows/block; thread = gate.
// Per step: 8 conflict-free ds_read_b128 (weights) + 16 broadcast b128 (h)
// + 64 v_dot4_i32_i8 + dequant (1 fmul).  Halves round-9's LDS data wall.
// ---------------------------------------------------------------------------
__global__ void __launch_bounds__(512, 1)
kRecL8(const _Float16* __restrict__ gin, const uint4* __restrict__ wq8,
       const float* __restrict__ mscale, _Float16* __restrict__ hout)
{
    __shared__ uint4 wlds[8 * 512];                 // 64 KB int8 weights
    __shared__ float sg[2][G4];                     // 4 KB
    __shared__ __align__(16) u32 hq[2][32];         // 256 B int8 h (2 rows)
    const int g  = threadIdx.x;
    const int b0 = blockIdx.x * 2;

    for (int i = g; i < 8 * 512; i += 512) wlds[i] = wq8[i];
    if (g < 64) ((u32*)hq)[g] = 0;

    const float m = mscale[g];
    const int r_ = g >> 7, hd_ = g & 127;
    float c_reg = 0.f;
    const _Float16* gb0 = gin + (size_t)(b0 + 0) * L_ * G4 + g;
    const _Float16* gb1 = gin + (size_t)(b0 + 1) * L_ * G4 + g;
    float p0 = (float)*gb0, p1 = (float)*gb1;
    __syncthreads();

    for (int l = 0; l < L_; ++l) {
        int ln = (l < L_ - 1) ? l + 1 : l;
        float n0 = (float)gb0[(size_t)ln * G4];
        float n1 = (float)gb1[(size_t)ln * G4];
        int acc0 = 0, acc1 = 0;
        const uint4* h0q = (const uint4*)hq[0];
        const uint4* h1q = (const uint4*)hq[1];
#pragma unroll
        for (int j8 = 0; j8 < 8; ++j8) {
            uint4 wq = wlds[j8 * 512 + g];
            uint4 ha = h0q[j8], hb = h1q[j8];
            acc0 = sdot4i(wq.x, ha.x, acc0); acc0 = sdot4i(wq.y, ha.y, acc0);
            acc0 = sdot4i(wq.z, ha.z, acc0); acc0 = sdot4i(wq.w, ha.w, acc0);
            acc1 = sdot4i(wq.x, hb.x, acc1); acc1 = sdot4i(wq.y, hb.y, acc1);
            acc1 = sdot4i(wq.z, hb.z, acc1); acc1 = sdot4i(wq.w, hb.w, acc1);
        }
        sg[0][g] = p0 + m * (float)acc0;
        sg[1][g] = p1 + m * (float)acc1;
        __syncthreads();
        if (g < 256) {
            float gi = sg[r_][hd_], gf = sg[r_][H_ + hd_];
            float gg = sg[r_][2 * H_ + hd_], go = sg[r_][3 * H_ + hd_];
            float c = sigm(gf) * c_reg + sigm(gi) * tanh_f(gg);
            float h = sigm(go) * tanh_f(c);
            c_reg = c;
            int qv = (int)rintf(h * 127.f);
            ((signed char*)hq[r_])[hd_] = (signed char)qv;
            hout[((size_t)(b0 + r_) * L_ + l) * H_ + hd_] = (_Float16)h;
        }
        __syncthreads();
        p0 = n0; p1 = n1;
    }
}

// ---------------------------------------------------------------------------
// kX2: fused epilogue.  afterx from h2 (f16 dot2), px/pt from etab(f16)+ttab.
// ---------------------------------------------------------------------------
__global__ void __launch_bounds__(256)
kX2(const int* __restrict__ x, const int* __restrict__ dpt,
    const int* __restrict__ adj, const __half* __restrict__ h2seq,
    const u32* __restrict__ wap, const float* __restrict__ bax,
    const _Float16* __restrict__ etab, const float* __restrict__ ttab,
    float* __restrict__ pred_x, float* __restrict__ pred_t)
{
    __shared__ uint4 swp[512];
    __shared__ float stt[48 * 96];
    __shared__ float sbax[32];
    int tid = threadIdx.x;
    for (int i = tid; i < 512; i += 256) swp[i] = ((const uint4*)wap)[i];
    for (int i = tid; i < 4608; i += 256) stt[i] = ttab[i];
    if (tid < 32) sbax[tid] = bax[tid];
    __syncthreads();

    int bl = blockIdx.x * 256 + tid;
    int xt = x[bl], dt = dpt[bl];

    uint4 h2r[16];
    const uint4* h2p = (const uint4*)(h2seq + (size_t)bl * H_);
#pragma unroll
    for (int q = 0; q < 16; ++q) h2r[q] = h2p[q];

    float afterx[OD];
    for (int o = 0; o < OD; ++o) {
        float acc = sbax[o];
#pragma unroll
        for (int q = 0; q < 16; ++q) {
            uint4 w = swp[o * 16 + q];
            acc = dot2f(w.x, h2r[q].x, acc);
            acc = dot2f(w.y, h2r[q].y, acc);
            acc = dot2f(w.z, h2r[q].z, acc);
            acc = dot2f(w.w, h2r[q].w, acc);
        }
        afterx[o] = acc > 0.f ? acc : 0.f;
    }

    const float* tB = stt + dt * 96;
    float px[K_];
#pragma unroll
    for (int k = 0; k < K_; ++k) {
        int a = adj[xt * K_ + k];
        int ac = a < NE ? a : 0;
        const uint4* ep = (const uint4*)(etab + (size_t)ac * 96);  // 12 uint4
        float sx = 0.f, st = 0.f;
#pragma unroll
        for (int q = 0; q < 4; ++q) {
            uint4 e = ep[q];
            f32x4 e0 = cvt4h(e.x, e.y);
            f32x4 e1 = cvt4h(e.z, e.w);
#pragma unroll
            for (int j = 0; j < 4; ++j) {
                sx += afterx[q * 8 + j]     * (e0[j] + tB[q * 8 + j]);
                sx += afterx[q * 8 + 4 + j] * (e1[j] + tB[q * 8 + 4 + j]);
            }
        }
#pragma unroll
        for (int q = 0; q < 4; ++q) {
            uint4 em4 = ep[4 + q], ea4 = ep[8 + q];
            f32x4 m0 = cvt4h(em4.x, em4.y), m1 = cvt4h(em4.z, em4.w);
            f32x4 a0 = cvt4h(ea4.x, ea4.y), a1 = cvt4h(ea4.z, ea4.w);
#pragma unroll
            for (int j = 0; j < 4; ++j) {
                float at0 = fmaxf(a0[j] + tB[64 + q * 8 + j], 0.f);
                float at1 = fmaxf(a1[j] + tB[64 + q * 8 + 4 + j], 0.f);
                st += at0 * (m0[j] + tB[32 + q * 8 + j]);
                st += at1 * (m1[j] + tB[32 + q * 8 + 4 + j]);
            }
        }
        px[k] = (a == NE) ? -INFINITY : sx;
        pred_t[(size_t)bl * K_ + k] = 1.f / (1.f + expf(-st));
    }

    float m = px[0];
#pragma unroll
    for (int k = 1; k < K_; ++k) m = fmaxf(m, px[k]);
    float ssum = 0.f;
#pragma unroll
    for (int k = 0; k < K_; ++k) ssum += expf(px[k] - m);
    float lse = logf(ssum) + m;
#pragma unroll
    for (int k = 0; k < K_; ++k)
        pred_x[(size_t)bl * K_ + k] = px[k] - lse;
}

// ---------------------------------------------------------------------------
extern "C" void kernel_launch(void* const* d_in, const int* in_sizes, int n_in,
                              void* d_out, int out_size, void* d_ws, size_t ws_size,
                              hipStream_t stream)
{
    (void)in_sizes; (void)n_in; (void)out_size; (void)ws_size;

    const int*   x      = (const int*)  d_in[0];
    const int*   dpt    = (const int*)  d_in[1];
    const float* z      = (const float*)d_in[2];
    const int*   adj    = (const int*)  d_in[3];
    const float* eprop  = (const float*)d_in[4];
    const float* x_emb  = (const float*)d_in[5];
    const float* t_emb  = (const float*)d_in[6];
    const float* tcost  = (const float*)d_in[7];
    const float* w_ih0  = (const float*)d_in[8];
    const float* w_hh0  = (const float*)d_in[9];
    const float* b_ih0  = (const float*)d_in[10];
    const float* b_hh0  = (const float*)d_in[11];
    const float* w_ih1  = (const float*)d_in[12];
    const float* w_hh1  = (const float*)d_in[13];
    const float* b_ih1  = (const float*)d_in[14];
    const float* b_hh1  = (const float*)d_in[15];
    const float* w_ih2  = (const float*)d_in[16];
    const float* w_hh2  = (const float*)d_in[17];
    const float* b_ih2  = (const float*)d_in[18];
    const float* b_hh2  = (const float*)d_in[19];
    const float* wax    = (const float*)d_in[20];
    const float* bax    = (const float*)d_in[21];
    const float* wat    = (const float*)d_in[22];
    const float* bat    = (const float*)d_in[23];
    const float* wmx    = (const float*)d_in[24];
    const float* bmx    = (const float*)d_in[25];
    const float* wmt    = (const float*)d_in[26];
    const float* bmt    = (const float*)d_in[27];

    float* out    = (float*)d_out;
    float* pred_x = out;
    float* pred_t = out + (size_t)B_ * L_ * K_;

    u32* wsu = (u32*)d_ws;
    u32* wih0p = wsu;                 // 49152
    u32* q0    = wsu + 49152;         // int8 tables layer0 (16384) + msc (512)
    u32* wih1p = wsu + 81920;
    u32* q1    = wsu + 114688;
    u32* wih2p = wsu + 147456;
    u32* q2    = wsu + 180224;
    u32* wap   = wsu + 212992;
    u32* wmxp  = wsu + 215040;
    u32* wmtp  = wsu + 217216;
    u32* watp0 = wsu + 219392;
    float* bsum = (float*)(wsu + 219904);           // [3][512]
    u32* A0    = wsu + 221440;                      // 65536*96
    _Float16* gin   = (_Float16*)(wsu + 6512896);   // 65536*512 f16
    _Float16* h0seq = (_Float16*)(wsu + 23290112);  // 65536*128 f16
    _Float16* h1seq = (_Float16*)(wsu + 27484416);
    _Float16* h2seq = (_Float16*)(wsu + 31678720);
    _Float16* etab  = (_Float16*)(wsu + 35873024);  // 50000*96 f16
    float* ttab = (float*)(wsu + 40673024);         // 4608

    kW2<<<865, 256, 0, stream>>>(w_ih0, w_hh0, w_ih1, w_hh1, w_ih2, w_hh2,
                                 wax, wmx, wmt, wat,
                                 b_ih0, b_hh0, b_ih1, b_hh1, b_ih2, b_hh2, wsu);

    kQ<<<6, 256, 0, stream>>>(w_hh0, w_hh1, w_hh2, wsu);

    kT<<<18, 256, 0, stream>>>(t_emb, wmx, wmt, wat, bmx, bmt, bat, ttab);

    kE<<<196, 256, 0, stream>>>(x_emb, eprop, tcost, wmxp, wmtp, watp0, etab);

    kAP<<<512, 512, 0, stream>>>(x, dpt, z, eprop, x_emb, t_emb, A0);

    kGm<6><<<1024, 512, 0, stream>>>((const _Float16*)A0, wih0p, bsum + 0, gin);
    kRecL8<<<256, 512, 0, stream>>>(gin, (const uint4*)q0, (const float*)(q0 + 16384), h0seq);

    kGm<4><<<1024, 512, 0, stream>>>(h0seq, wih1p, bsum + 512, gin);
    kRecL8<<<256, 512, 0, stream>>>(gin, (const uint4*)q1, (const float*)(q1 + 16384), h1seq);

    kGm<4><<<1024, 512, 0, stream>>>(h1seq, wih2p, bsum + 1024, gin);
    kRecL8<<<256, 512, 0, stream>>>(gin, (const uint4*)q2, (const float*)(q2 + 16384), h2seq);

    kX2<<<256, 256, 0, stream>>>(x, dpt, adj, (const __half*)h2seq, wap, bax,
                                 etab, ttab, pred_x, pred_t);
}